// Round 2
// baseline (556.327 us; speedup 1.0000x reference)
//
#include <hip/hip_runtime.h>
#include <hip/hip_fp16.h>

#define NB   128
#define SPB_ 512
#define NPOS 131072   // 128*32*32
#define NBIN 256      // packed bins: plane 0 holds (bin0, bin256)
#define PI_F 3.14159265358979323846f
#define R2_F 0.70710678118654752f

static __device__ __forceinline__ float clamp01(float v) {
    return fminf(fmaxf(v, 0.0f), 1.0f);
}
// XOR-swizzle for the per-wave float2 Z buffer: conflicting scatter lanes
// differ exactly in bits 4..5 of the bit-reversed index -> fold into low bits.
static __device__ __forceinline__ int zidx(int v) { return v ^ ((v >> 4) & 3); }

// ---------------------------------------------------------------------------
// K1: per-position H[k] = clip(tf)[k] * rfft_unnorm(env)[k], stored as f16,
// layout Hbuf[k][pos]. 256 thr = 4 waves; 16 positions/block in 2 rounds of
// (2 positions per wave, interleaved for ILP). All twiddles derived from 6
// hoisted per-lane sincos via constant complex rotations (zero in-loop trans).
// ---------------------------------------------------------------------------
__global__ __launch_bounds__(256, 4) void k1_fft(
    const float* __restrict__ tf,    // [NPOS][257]
    const float* __restrict__ imp,   // [NPOS][16]
    const float* __restrict__ nz,    // [NPOS][512]
    __half2* __restrict__ Hbuf)      // [NBIN][NPOS]
{
    __shared__ float2  Zb[4][2][256];   // per-wave, per-position (A/B)
    __shared__ float   ldsImp[256];
    __shared__ __half2 stg[8][265];     // stride 265: (9*rr+k)%32 readout banks

    const int tid  = threadIdx.x;
    const int wv   = tid >> 6;
    const int lane = tid & 63;
    const int pos0 = blockIdx.x << 4;

    ldsImp[tid] = imp[(size_t)pos0 * 16 + tid];

    // ---- hoisted per-lane twiddle bases (the ONLY sincos in this kernel) ----
    float bc[5], bs[5];
    #pragma unroll
    for (int t = 0; t < 5; ++t) {
        const int s = 128 >> t;
        float ang = -PI_F * (float)((4 * lane) & (s - 1)) / (float)s;
        __sincosf(ang, &bs[t], &bc[t]);
    }
    float uc, us;   // exp(-i*pi*lane/256) for the untangle
    __sincosf(-PI_F * (1.0f / 256.0f) * (float)lane, &us, &uc);

    // ---- hoisted env-interpolation coefficients (lane covers t=8L..8L+7) ----
    float fru[8]; int j0u[8];
    #pragma unroll
    for (int u = 0; u < 8; ++u) {
        float p = ((float)(lane * 8 + u) - 15.5f) * (1.0f / 32.0f);
        p = fminf(fmaxf(p, 0.0f), 15.0f);
        int j0 = (int)p; j0 = j0 > 14 ? 14 : j0;
        j0u[u] = j0; fru[u] = p - (float)j0;
    }

    // constant j-rotations exp(-i*pi*j/s), s=128,64,32,16,8; j=1..3
    const float wjc[5][3] = {
        {0.99969882f, 0.99879546f, 0.99729046f},
        {0.99879546f, 0.99518473f, 0.98917651f},
        {0.99518473f, 0.98078528f, 0.95694034f},
        {0.98078528f, 0.92387953f, 0.83146961f},
        {0.92387953f, 0.70710678f, 0.38268343f}};
    const float wjs[5][3] = {
        {-0.02454123f, -0.04906767f, -0.07356456f},
        {-0.04906767f, -0.09801714f, -0.14673047f},
        {-0.09801714f, -0.19509032f, -0.29028468f},
        {-0.19509032f, -0.38268343f, -0.55557023f},
        {-0.38268343f, -0.70710678f, -0.92387953f}};

    __syncthreads();

    auto envload = [&](int pos, int g, float er[4], float ei[4]) {
        const float* nzp = nz + (size_t)pos * SPB_ + lane * 8;
        float4 n0 = *(const float4*)nzp;
        float4 n1 = *(const float4*)(nzp + 4);
        float nvv[8] = {n0.x, n0.y, n0.z, n0.w, n1.x, n1.y, n1.z, n1.w};
        const int base = g << 4;
        #pragma unroll
        for (int u = 0; u < 8; ++u) {
            float a  = ldsImp[base + j0u[u]];
            float b  = ldsImp[base + j0u[u] + 1];
            float e  = clamp01(fmaf(fru[u], b - a, a)) * nvv[u];
            if (u & 1) ei[u >> 1] = e; else er[u >> 1] = e;
        }
    };

    auto stage4 = [&](float er[4], float ei[4]) {   // s=4, lm=1, const twiddles
        const bool rb = (lane & 1) != 0;
        #pragma unroll
        for (int j = 0; j < 4; ++j) {
            float ro = __shfl_xor(er[j], 1, 64), io = __shfl_xor(ei[j], 1, 64);
            float sr = er[j] + ro, si = ei[j] + io;
            float dr = ro - er[j], di = io - ei[j];
            float tr, ti;
            if      (j == 0) { tr = dr;               ti = di; }
            else if (j == 1) { tr = R2_F * (dr + di); ti = R2_F * (di - dr); }
            else if (j == 2) { tr = di;               ti = -dr; }
            else             { tr = R2_F * (di - dr); ti = -R2_F * (dr + di); }
            er[j] = rb ? tr : sr; ei[j] = rb ? ti : si;
        }
    };

    auto stage21 = [&](float er[4], float ei[4]) {  // local s=2 then s=1
        float ar, ai, br, bi, dr, di;
        ar = er[0]; ai = ei[0]; br = er[2]; bi = ei[2];
        er[0] = ar + br; ei[0] = ai + bi; er[2] = ar - br; ei[2] = ai - bi;
        ar = er[1]; ai = ei[1]; br = er[3]; bi = ei[3];
        er[1] = ar + br; ei[1] = ai + bi;
        dr = ar - br; di = ai - bi; er[3] = di; ei[3] = -dr;   // * (-i)
        ar = er[0]; ai = ei[0]; br = er[1]; bi = ei[1];
        er[0] = ar + br; ei[0] = ai + bi; er[1] = ar - br; ei[1] = ai - bi;
        ar = er[2]; ai = ei[2]; br = er[3]; bi = ei[3];
        er[2] = ar + br; ei[2] = ai + bi; er[3] = ar - br; ei[3] = ai - bi;
    };

    auto scatter = [&](const float er[4], const float ei[4], float2* Z) {
        #pragma unroll
        for (int j = 0; j < 4; ++j) {
            int p   = (lane << 2) | j;
            int rev = __brev((unsigned)p) >> 24;
            Z[zidx(rev)] = make_float2(er[j], ei[j]);
        }
    };

    auto untangle = [&](const float2* Z, const float* tfp, int row) {
        #pragma unroll
        for (int m = 0; m < 4; ++m) {
            int k = lane + (m << 6);
            if (k == 0) {
                float2 z0 = Z[0];
                stg[row][0] = __floats2half2_rn(clamp01(tfp[0])   * (z0.x + z0.y),
                                                clamp01(tfp[256]) * (z0.x - z0.y));
            } else {
                float2 zk = Z[zidx(k)], zm = Z[zidx(256 - k)];
                float Er = 0.5f * (zk.x + zm.x), Ei = 0.5f * (zk.y - zm.y);
                float Or = 0.5f * (zk.y + zm.y), Oi = -0.5f * (zk.x - zm.x);
                float cv, sv;
                if      (m == 0) { cv = uc;               sv = us; }
                else if (m == 1) { cv = R2_F * (uc + us); sv = R2_F * (us - uc); }
                else if (m == 2) { cv = us;               sv = -uc; }
                else             { cv = R2_F * (us - uc); sv = -R2_F * (uc + us); }
                float Xr = Er + cv * Or - sv * Oi;
                float Xi = Ei + cv * Oi + sv * Or;
                float rk = clamp01(tfp[k]);
                stg[row][k] = __floats2half2_rn(rk * Xr, rk * Xi);
            }
        }
    };

    for (int q = 0; q < 2; ++q) {
        const int rA   = wv << 1;
        const int g    = (q << 3) + rA;
        const int posA = pos0 + g, posB = posA + 1;

        float erA[4], eiA[4], erB[4], eiB[4];
        envload(posA, g,     erA, eiA);
        envload(posB, g + 1, erB, eiB);

        // ----- 5 cross-lane stages with derived twiddles (A,B interleaved) --
        #pragma unroll
        for (int t = 0; t < 5; ++t) {
            const int  lm = 32 >> t;
            const bool rb = (lane & lm) != 0;
            const float c0 = bc[t], s0 = bs[t];
            #pragma unroll
            for (int j = 0; j < 4; ++j) {
                float c, sn;
                if (j == 0) { c = c0; sn = s0; }
                else {
                    const float wc = wjc[t][j - 1], ws = wjs[t][j - 1];
                    c  = c0 * wc - s0 * ws;
                    sn = c0 * ws + s0 * wc;
                }
                {   // A
                    float ro = __shfl_xor(erA[j], lm, 64), io = __shfl_xor(eiA[j], lm, 64);
                    float sr = erA[j] + ro, si = eiA[j] + io;
                    float dr = ro - erA[j], di = io - eiA[j];
                    float tr = c * dr - sn * di, ti = c * di + sn * dr;
                    erA[j] = rb ? tr : sr; eiA[j] = rb ? ti : si;
                }
                {   // B
                    float ro = __shfl_xor(erB[j], lm, 64), io = __shfl_xor(eiB[j], lm, 64);
                    float sr = erB[j] + ro, si = eiB[j] + io;
                    float dr = ro - erB[j], di = io - eiB[j];
                    float tr = c * dr - sn * di, ti = c * di + sn * dr;
                    erB[j] = rb ? tr : sr; eiB[j] = rb ? ti : si;
                }
            }
        }
        stage4(erA, eiA);  stage4(erB, eiB);
        stage21(erA, eiA); stage21(erB, eiB);

        scatter(erA, eiA, &Zb[wv][0][0]);
        scatter(erB, eiB, &Zb[wv][1][0]);
        untangle(&Zb[wv][0][0], tf + (size_t)posA * 257, rA);
        untangle(&Zb[wv][1][0], tf + (size_t)posB * 257, rA + 1);

        __syncthreads();
        {   // coalesced write-out: 8 consecutive pos (32B) per k
            const int rr = tid & 7, kb = tid >> 3;
            const size_t pbase = (size_t)pos0 + (q << 3) + rr;
            #pragma unroll
            for (int i = 0; i < 8; ++i) {
                int k = kb + (i << 5);
                Hbuf[(size_t)k * NPOS + pbase] = stg[rr][k];
            }
        }
        __syncthreads();
    }
}

// ---------------------------------------------------------------------------
// K2: frequency-domain scan. Block k owns bin-plane k: 32x32 complex state.
// Double-buffered LDS tile -> 1 barrier/step; prefetch depth 2.
// ---------------------------------------------------------------------------
__global__ __launch_bounds__(1024) void k2_scan(
    const __half2* __restrict__ Hbuf,  // [NBIN][NPOS]
    float2* __restrict__ Mbuf)         // [NB][NBIN]
{
    __shared__ float2 sfb[2][32][33];
    const int k   = blockIdx.x;
    const int tid = threadIdx.x;
    const int h   = tid >> 5, w = tid & 31;
    const int hm = (h == 0) ? 1 : h - 1, hp = (h == 31) ? 30 : h + 1;
    const int wm = (w == 0) ? 1 : w - 1, wp = (w == 31) ? 30 : w + 1;

    const __half2* Hp = Hbuf + (size_t)k * NPOS + tid;
    __half2 c0 = Hp[0];
    __half2 c1 = Hp[1024];
    float fr = 0.0f, fi = 0.0f;

    for (int b = 0; b < NB; ++b) {
        float2 hv = __half22float2(c0);
        c0 = c1;
        if (b + 2 < NB) c1 = Hp[(size_t)(b + 2) << 10];
        fr += hv.x; fi += hv.y;
        if (tid == 528) Mbuf[b * NBIN + k] = make_float2(fr, fi); // mic BEFORE box
        sfb[b & 1][h][w] = make_float2(fr, fi);
        __syncthreads();
        float sr = 0.0f, si = 0.0f; float2 v;
        v = sfb[b & 1][hm][wm]; sr += v.x; si += v.y;
        v = sfb[b & 1][hm][w ]; sr += v.x; si += v.y;
        v = sfb[b & 1][hm][wp]; sr += v.x; si += v.y;
        v = sfb[b & 1][h ][wm]; sr += v.x; si += v.y;
        v = sfb[b & 1][h ][w ]; sr += v.x; si += v.y;
        v = sfb[b & 1][h ][wp]; sr += v.x; si += v.y;
        v = sfb[b & 1][hp][wm]; sr += v.x; si += v.y;
        v = sfb[b & 1][hp][w ]; sr += v.x; si += v.y;
        v = sfb[b & 1][hp][wp]; sr += v.x; si += v.y;
        fr = sr * (1.0f / 9.0f); fi = si * (1.0f / 9.0f);
    }
}

// ---------------------------------------------------------------------------
// K3: per-block-b inverse rDFT (512 samples from 257 Hermitian bins, 1/512).
// ---------------------------------------------------------------------------
__global__ __launch_bounds__(512) void k3_idft(
    const float2* __restrict__ Mbuf,
    float* __restrict__ out)
{
    __shared__ float2 lm[256];
    const int b = blockIdx.x;
    const int t = threadIdx.x;
    if (t < 256) lm[t] = Mbuf[b * NBIN + t];
    __syncthreads();
    float acc = 0.0f;
    #pragma unroll 4
    for (int k = 1; k < 256; ++k) {
        int   ph  = (k * t) & 511;
        float ang = (float)ph * (PI_F / 256.0f);
        float sv, cv; __sincosf(ang, &sv, &cv);
        float2 m = lm[k];
        acc += m.x * cv - m.y * sv;
    }
    float m0 = lm[0].x, m256 = lm[0].y;
    float r  = m0 + ((t & 1) ? -m256 : m256) + 2.0f * acc;
    out[(b << 9) + t] = r * (1.0f / 512.0f);
}

extern "C" void kernel_launch(void* const* d_in, const int* in_sizes, int n_in,
                              void* d_out, int out_size, void* d_ws, size_t ws_size,
                              hipStream_t stream)
{
    const float* tf  = (const float*)d_in[1]; // (128,32,32,257)
    const float* imp = (const float*)d_in[2]; // (128,32,32,16)
    const float* nz  = (const float*)d_in[3]; // (128,32,32,512)
    float* out = (float*)d_out;

    const size_t hbytes = (size_t)NBIN * NPOS * sizeof(__half2);  // 134.2 MB
    const size_t mbytes = (size_t)NB * NBIN * sizeof(float2);     // 256 KB
    if (ws_size < hbytes + mbytes) {
        hipMemsetAsync(d_out, 0xFF, (size_t)out_size * sizeof(float), stream);
        return;
    }
    __half2* Hbuf = (__half2*)d_ws;
    float2*  Mbuf = (float2*)((char*)d_ws + hbytes);

    k1_fft<<<NPOS / 16, 256, 0, stream>>>(tf, imp, nz, Hbuf);
    k2_scan<<<NBIN, 1024, 0, stream>>>(Hbuf, Mbuf);
    k3_idft<<<NB, 512, 0, stream>>>(Mbuf, out);
}

// Round 3
// 432.938 us; speedup vs baseline: 1.2850x; 1.2850x over previous
//
#include <hip/hip_runtime.h>
#include <hip/hip_fp16.h>

#define NB   128
#define SPB_ 512
#define NPOS 131072   // 128*32*32
#define NBIN 256      // packed bins: plane 0 holds (bin0, bin256)
#define PI_F 3.14159265358979323846f
#define R2_F 0.70710678118654752f

static __device__ __forceinline__ float clamp01(float v) {
    return fminf(fmaxf(v, 0.0f), 1.0f);
}
// XOR-swizzle for the per-wave float2 Z buffer: conflicting scatter lanes
// differ exactly in bits 4..5 of the bit-reversed index -> fold into low bits.
static __device__ __forceinline__ int zidx(int v) { return v ^ ((v >> 4) & 3); }

// ---------------------------------------------------------------------------
// K1: per-position H[k] = clip(tf)[k] * rfft_unnorm(env)[k], stored as f16,
// layout Hbuf[k][pos]. 256 thr = 4 waves; 16 positions/block in 2 rounds of
// (2 positions per wave, interleaved for ILP). All twiddles derived from 6
// hoisted per-lane sincos via constant complex rotations (zero in-loop trans).
// All 16 rows staged in LDS; ONE write-out with 64B-per-16-lane full lines.
// ---------------------------------------------------------------------------
__global__ __launch_bounds__(256, 4) void k1_fft(
    const float* __restrict__ tf,    // [NPOS][257]
    const float* __restrict__ imp,   // [NPOS][16]
    const float* __restrict__ nz,    // [NPOS][512]
    __half2* __restrict__ Hbuf)      // [NBIN][NPOS]
{
    __shared__ float2  Zb[4][2][256];   // per-wave, per-position (A/B)
    __shared__ float   ldsImp[256];
    __shared__ __half2 stg[16][265];    // stride 265 (odd): readout ~2-way max

    const int tid  = threadIdx.x;
    const int wv   = tid >> 6;
    const int lane = tid & 63;
    const int pos0 = blockIdx.x << 4;

    ldsImp[tid] = imp[(size_t)pos0 * 16 + tid];

    // ---- hoisted per-lane twiddle bases (the ONLY sincos in this kernel) ----
    float bc[5], bs[5];
    #pragma unroll
    for (int t = 0; t < 5; ++t) {
        const int s = 128 >> t;
        float ang = -PI_F * (float)((4 * lane) & (s - 1)) / (float)s;
        __sincosf(ang, &bs[t], &bc[t]);
    }
    float uc, us;   // exp(-i*pi*lane/256) for the untangle
    __sincosf(-PI_F * (1.0f / 256.0f) * (float)lane, &us, &uc);

    // ---- hoisted env-interpolation coefficients (lane covers t=8L..8L+7) ----
    float fru[8]; int j0u[8];
    #pragma unroll
    for (int u = 0; u < 8; ++u) {
        float p = ((float)(lane * 8 + u) - 15.5f) * (1.0f / 32.0f);
        p = fminf(fmaxf(p, 0.0f), 15.0f);
        int j0 = (int)p; j0 = j0 > 14 ? 14 : j0;
        j0u[u] = j0; fru[u] = p - (float)j0;
    }

    // constant j-rotations exp(-i*pi*j/s), s=128,64,32,16,8; j=1..3
    const float wjc[5][3] = {
        {0.99969882f, 0.99879546f, 0.99729046f},
        {0.99879546f, 0.99518473f, 0.98917651f},
        {0.99518473f, 0.98078528f, 0.95694034f},
        {0.98078528f, 0.92387953f, 0.83146961f},
        {0.92387953f, 0.70710678f, 0.38268343f}};
    const float wjs[5][3] = {
        {-0.02454123f, -0.04906767f, -0.07356456f},
        {-0.04906767f, -0.09801714f, -0.14673047f},
        {-0.09801714f, -0.19509032f, -0.29028468f},
        {-0.19509032f, -0.38268343f, -0.55557023f},
        {-0.38268343f, -0.70710678f, -0.92387953f}};

    __syncthreads();

    auto envload = [&](int pos, int g, float er[4], float ei[4]) {
        const float* nzp = nz + (size_t)pos * SPB_ + lane * 8;
        float4 n0 = *(const float4*)nzp;
        float4 n1 = *(const float4*)(nzp + 4);
        float nvv[8] = {n0.x, n0.y, n0.z, n0.w, n1.x, n1.y, n1.z, n1.w};
        const int base = g << 4;
        #pragma unroll
        for (int u = 0; u < 8; ++u) {
            float a  = ldsImp[base + j0u[u]];
            float b  = ldsImp[base + j0u[u] + 1];
            float e  = clamp01(fmaf(fru[u], b - a, a)) * nvv[u];
            if (u & 1) ei[u >> 1] = e; else er[u >> 1] = e;
        }
    };

    auto stage4 = [&](float er[4], float ei[4]) {   // s=4, lm=1, const twiddles
        const bool rb = (lane & 1) != 0;
        #pragma unroll
        for (int j = 0; j < 4; ++j) {
            float ro = __shfl_xor(er[j], 1, 64), io = __shfl_xor(ei[j], 1, 64);
            float sr = er[j] + ro, si = ei[j] + io;
            float dr = ro - er[j], di = io - ei[j];
            float tr, ti;
            if      (j == 0) { tr = dr;               ti = di; }
            else if (j == 1) { tr = R2_F * (dr + di); ti = R2_F * (di - dr); }
            else if (j == 2) { tr = di;               ti = -dr; }
            else             { tr = R2_F * (di - dr); ti = -R2_F * (dr + di); }
            er[j] = rb ? tr : sr; ei[j] = rb ? ti : si;
        }
    };

    auto stage21 = [&](float er[4], float ei[4]) {  // local s=2 then s=1
        float ar, ai, br, bi, dr, di;
        ar = er[0]; ai = ei[0]; br = er[2]; bi = ei[2];
        er[0] = ar + br; ei[0] = ai + bi; er[2] = ar - br; ei[2] = ai - bi;
        ar = er[1]; ai = ei[1]; br = er[3]; bi = ei[3];
        er[1] = ar + br; ei[1] = ai + bi;
        dr = ar - br; di = ai - bi; er[3] = di; ei[3] = -dr;   // * (-i)
        ar = er[0]; ai = ei[0]; br = er[1]; bi = ei[1];
        er[0] = ar + br; ei[0] = ai + bi; er[1] = ar - br; ei[1] = ai - bi;
        ar = er[2]; ai = ei[2]; br = er[3]; bi = ei[3];
        er[2] = ar + br; ei[2] = ai + bi; er[3] = ar - br; ei[3] = ai - bi;
    };

    auto scatter = [&](const float er[4], const float ei[4], float2* Z) {
        #pragma unroll
        for (int j = 0; j < 4; ++j) {
            int p   = (lane << 2) | j;
            int rev = __brev((unsigned)p) >> 24;
            Z[zidx(rev)] = make_float2(er[j], ei[j]);
        }
    };

    auto untangle = [&](const float2* Z, const float* tfp, int row) {
        #pragma unroll
        for (int m = 0; m < 4; ++m) {
            int k = lane + (m << 6);
            if (k == 0) {
                float2 z0 = Z[0];
                stg[row][0] = __floats2half2_rn(clamp01(tfp[0])   * (z0.x + z0.y),
                                                clamp01(tfp[256]) * (z0.x - z0.y));
            } else {
                float2 zk = Z[zidx(k)], zm = Z[zidx(256 - k)];
                float Er = 0.5f * (zk.x + zm.x), Ei = 0.5f * (zk.y - zm.y);
                float Or = 0.5f * (zk.y + zm.y), Oi = -0.5f * (zk.x - zm.x);
                float cv, sv;
                if      (m == 0) { cv = uc;               sv = us; }
                else if (m == 1) { cv = R2_F * (uc + us); sv = R2_F * (us - uc); }
                else if (m == 2) { cv = us;               sv = -uc; }
                else             { cv = R2_F * (us - uc); sv = -R2_F * (uc + us); }
                float Xr = Er + cv * Or - sv * Oi;
                float Xi = Ei + cv * Oi + sv * Or;
                float rk = clamp01(tfp[k]);
                stg[row][k] = __floats2half2_rn(rk * Xr, rk * Xi);
            }
        }
    };

    for (int q = 0; q < 2; ++q) {
        const int rA   = (q << 3) + (wv << 1);     // rows rA, rA+1
        const int posA = pos0 + rA, posB = posA + 1;

        float erA[4], eiA[4], erB[4], eiB[4];
        envload(posA, rA,     erA, eiA);
        envload(posB, rA + 1, erB, eiB);

        // ----- 5 cross-lane stages with derived twiddles (A,B interleaved) --
        #pragma unroll
        for (int t = 0; t < 5; ++t) {
            const int  lm = 32 >> t;
            const bool rb = (lane & lm) != 0;
            const float c0 = bc[t], s0 = bs[t];
            #pragma unroll
            for (int j = 0; j < 4; ++j) {
                float c, sn;
                if (j == 0) { c = c0; sn = s0; }
                else {
                    const float wc = wjc[t][j - 1], ws = wjs[t][j - 1];
                    c  = c0 * wc - s0 * ws;
                    sn = c0 * ws + s0 * wc;
                }
                {   // A
                    float ro = __shfl_xor(erA[j], lm, 64), io = __shfl_xor(eiA[j], lm, 64);
                    float sr = erA[j] + ro, si = eiA[j] + io;
                    float dr = ro - erA[j], di = io - eiA[j];
                    float tr = c * dr - sn * di, ti = c * di + sn * dr;
                    erA[j] = rb ? tr : sr; eiA[j] = rb ? ti : si;
                }
                {   // B
                    float ro = __shfl_xor(erB[j], lm, 64), io = __shfl_xor(eiB[j], lm, 64);
                    float sr = erB[j] + ro, si = eiB[j] + io;
                    float dr = ro - erB[j], di = io - eiB[j];
                    float tr = c * dr - sn * di, ti = c * di + sn * dr;
                    erB[j] = rb ? tr : sr; eiB[j] = rb ? ti : si;
                }
            }
        }
        stage4(erA, eiA);  stage4(erB, eiB);
        stage21(erA, eiA); stage21(erB, eiB);

        scatter(erA, eiA, &Zb[wv][0][0]);
        scatter(erB, eiB, &Zb[wv][1][0]);
        // wave-private Zb: intra-wave LDS ordering, no barrier needed
        untangle(&Zb[wv][0][0], tf + (size_t)posA * 257, rA);
        untangle(&Zb[wv][1][0], tf + (size_t)posB * 257, rA + 1);
    }

    __syncthreads();
    {   // single coalesced write-out: 16 consecutive pos (64B line) per k
        const int rr = tid & 15, kb = tid >> 4;
        const size_t pbase = (size_t)pos0 + rr;
        #pragma unroll
        for (int i = 0; i < 16; ++i) {
            int k = kb + (i << 4);
            Hbuf[(size_t)k * NPOS + pbase] = stg[rr][k];
        }
    }
}

// ---------------------------------------------------------------------------
// K2: frequency-domain scan. Block k owns bin-plane k: 32x32 complex state.
// Double-buffered LDS tile -> 1 barrier/step; prefetch depth 2.
// ---------------------------------------------------------------------------
__global__ __launch_bounds__(1024) void k2_scan(
    const __half2* __restrict__ Hbuf,  // [NBIN][NPOS]
    float2* __restrict__ Mbuf)         // [NB][NBIN]
{
    __shared__ float2 sfb[2][32][33];
    const int k   = blockIdx.x;
    const int tid = threadIdx.x;
    const int h   = tid >> 5, w = tid & 31;
    const int hm = (h == 0) ? 1 : h - 1, hp = (h == 31) ? 30 : h + 1;
    const int wm = (w == 0) ? 1 : w - 1, wp = (w == 31) ? 30 : w + 1;

    const __half2* Hp = Hbuf + (size_t)k * NPOS + tid;
    __half2 c0 = Hp[0];
    __half2 c1 = Hp[1024];
    float fr = 0.0f, fi = 0.0f;

    for (int b = 0; b < NB; ++b) {
        float2 hv = __half22float2(c0);
        c0 = c1;
        if (b + 2 < NB) c1 = Hp[(size_t)(b + 2) << 10];
        fr += hv.x; fi += hv.y;
        if (tid == 528) Mbuf[b * NBIN + k] = make_float2(fr, fi); // mic BEFORE box
        sfb[b & 1][h][w] = make_float2(fr, fi);
        __syncthreads();
        float sr = 0.0f, si = 0.0f; float2 v;
        v = sfb[b & 1][hm][wm]; sr += v.x; si += v.y;
        v = sfb[b & 1][hm][w ]; sr += v.x; si += v.y;
        v = sfb[b & 1][hm][wp]; sr += v.x; si += v.y;
        v = sfb[b & 1][h ][wm]; sr += v.x; si += v.y;
        v = sfb[b & 1][h ][w ]; sr += v.x; si += v.y;
        v = sfb[b & 1][h ][wp]; sr += v.x; si += v.y;
        v = sfb[b & 1][hp][wm]; sr += v.x; si += v.y;
        v = sfb[b & 1][hp][w ]; sr += v.x; si += v.y;
        v = sfb[b & 1][hp][wp]; sr += v.x; si += v.y;
        fr = sr * (1.0f / 9.0f); fi = si * (1.0f / 9.0f);
    }
}

// ---------------------------------------------------------------------------
// K3: per-block-b inverse rDFT (512 samples from 257 Hermitian bins, 1/512).
// ---------------------------------------------------------------------------
__global__ __launch_bounds__(512) void k3_idft(
    const float2* __restrict__ Mbuf,
    float* __restrict__ out)
{
    __shared__ float2 lm[256];
    const int b = blockIdx.x;
    const int t = threadIdx.x;
    if (t < 256) lm[t] = Mbuf[b * NBIN + t];
    __syncthreads();
    float acc = 0.0f;
    #pragma unroll 4
    for (int k = 1; k < 256; ++k) {
        int   ph  = (k * t) & 511;
        float ang = (float)ph * (PI_F / 256.0f);
        float sv, cv; __sincosf(ang, &sv, &cv);
        float2 m = lm[k];
        acc += m.x * cv - m.y * sv;
    }
    float m0 = lm[0].x, m256 = lm[0].y;
    float r  = m0 + ((t & 1) ? -m256 : m256) + 2.0f * acc;
    out[(b << 9) + t] = r * (1.0f / 512.0f);
}

extern "C" void kernel_launch(void* const* d_in, const int* in_sizes, int n_in,
                              void* d_out, int out_size, void* d_ws, size_t ws_size,
                              hipStream_t stream)
{
    const float* tf  = (const float*)d_in[1]; // (128,32,32,257)
    const float* imp = (const float*)d_in[2]; // (128,32,32,16)
    const float* nz  = (const float*)d_in[3]; // (128,32,32,512)
    float* out = (float*)d_out;

    const size_t hbytes = (size_t)NBIN * NPOS * sizeof(__half2);  // 134.2 MB
    const size_t mbytes = (size_t)NB * NBIN * sizeof(float2);     // 256 KB
    if (ws_size < hbytes + mbytes) {
        hipMemsetAsync(d_out, 0xFF, (size_t)out_size * sizeof(float), stream);
        return;
    }
    __half2* Hbuf = (__half2*)d_ws;
    float2*  Mbuf = (float2*)((char*)d_ws + hbytes);

    k1_fft<<<NPOS / 16, 256, 0, stream>>>(tf, imp, nz, Hbuf);
    k2_scan<<<NBIN, 1024, 0, stream>>>(Hbuf, Mbuf);
    k3_idft<<<NB, 512, 0, stream>>>(Mbuf, out);
}

// Round 4
// 297.924 us; speedup vs baseline: 1.8673x; 1.4532x over previous
//
#include <hip/hip_runtime.h>
#include <hip/hip_fp16.h>

#define NB   128
#define SPB_ 512
#define NPOS 131072   // 128*32*32
#define NBIN 256      // packed bins: plane 0 holds (bin0, bin256)
#define PI_F 3.14159265358979323846f
#define R2_F 0.70710678118654752f

static __device__ __forceinline__ float clamp01(float v) {
    return fminf(fmaxf(v, 0.0f), 1.0f);
}
// XOR-swizzle for the per-wave float2 Z buffer: conflicting scatter lanes
// differ exactly in bits 4..5 of the bit-reversed index -> fold into low bits.
static __device__ __forceinline__ int zidx(int v) { return v ^ ((v >> 4) & 3); }

// ---------------------------------------------------------------------------
// K1: per-position H[k] = clip(tf)[k] * rfft_unnorm(env)[k], stored as f16,
// layout Hbuf[k][pos]. 256 thr = 4 waves; 16 positions/block in 2 rounds of
// (2 positions per wave, interleaved for ILP). All twiddles derived from 6
// hoisted per-lane sincos via constant complex rotations (zero in-loop trans).
// All 16 rows staged in LDS; ONE write-out with 64B-per-16-lane full lines.
// NOTE: no min-waves clause — __launch_bounds__(256,4) capped VGPRs at 64 and
// spilled ~40 regs/thread (+320 MB scratch traffic, r2/r3 counters).
// ---------------------------------------------------------------------------
__global__ __launch_bounds__(256) void k1_fft(
    const float* __restrict__ tf,    // [NPOS][257]
    const float* __restrict__ imp,   // [NPOS][16]
    const float* __restrict__ nz,    // [NPOS][512]
    __half2* __restrict__ Hbuf)      // [NBIN][NPOS]
{
    __shared__ float2  Zb[4][2][256];   // per-wave, per-position (A/B)
    __shared__ float   ldsImp[256];
    __shared__ __half2 stg[16][265];    // stride 265 (odd): readout ~2-way max

    const int tid  = threadIdx.x;
    const int wv   = tid >> 6;
    const int lane = tid & 63;
    const int pos0 = blockIdx.x << 4;

    ldsImp[tid] = imp[(size_t)pos0 * 16 + tid];

    // ---- hoisted per-lane twiddle bases (the ONLY sincos in this kernel) ----
    float bc[5], bs[5];
    #pragma unroll
    for (int t = 0; t < 5; ++t) {
        const int s = 128 >> t;
        float ang = -PI_F * (float)((4 * lane) & (s - 1)) / (float)s;
        __sincosf(ang, &bs[t], &bc[t]);
    }
    float uc, us;   // exp(-i*pi*lane/256) for the untangle
    __sincosf(-PI_F * (1.0f / 256.0f) * (float)lane, &us, &uc);

    // ---- hoisted env-interpolation coefficients (lane covers t=8L..8L+7) ----
    float fru[8]; int j0u[8];
    #pragma unroll
    for (int u = 0; u < 8; ++u) {
        float p = ((float)(lane * 8 + u) - 15.5f) * (1.0f / 32.0f);
        p = fminf(fmaxf(p, 0.0f), 15.0f);
        int j0 = (int)p; j0 = j0 > 14 ? 14 : j0;
        j0u[u] = j0; fru[u] = p - (float)j0;
    }

    // constant j-rotations exp(-i*pi*j/s), s=128,64,32,16,8; j=1..3
    const float wjc[5][3] = {
        {0.99969882f, 0.99879546f, 0.99729046f},
        {0.99879546f, 0.99518473f, 0.98917651f},
        {0.99518473f, 0.98078528f, 0.95694034f},
        {0.98078528f, 0.92387953f, 0.83146961f},
        {0.92387953f, 0.70710678f, 0.38268343f}};
    const float wjs[5][3] = {
        {-0.02454123f, -0.04906767f, -0.07356456f},
        {-0.04906767f, -0.09801714f, -0.14673047f},
        {-0.09801714f, -0.19509032f, -0.29028468f},
        {-0.19509032f, -0.38268343f, -0.55557023f},
        {-0.38268343f, -0.70710678f, -0.92387953f}};

    __syncthreads();

    auto envload = [&](int pos, int g, float er[4], float ei[4]) {
        const float* nzp = nz + (size_t)pos * SPB_ + lane * 8;
        float4 n0 = *(const float4*)nzp;
        float4 n1 = *(const float4*)(nzp + 4);
        float nvv[8] = {n0.x, n0.y, n0.z, n0.w, n1.x, n1.y, n1.z, n1.w};
        const int base = g << 4;
        #pragma unroll
        for (int u = 0; u < 8; ++u) {
            float a  = ldsImp[base + j0u[u]];
            float b  = ldsImp[base + j0u[u] + 1];
            float e  = clamp01(fmaf(fru[u], b - a, a)) * nvv[u];
            if (u & 1) ei[u >> 1] = e; else er[u >> 1] = e;
        }
    };

    auto stage4 = [&](float er[4], float ei[4]) {   // s=4, lm=1, const twiddles
        const bool rb = (lane & 1) != 0;
        #pragma unroll
        for (int j = 0; j < 4; ++j) {
            float ro = __shfl_xor(er[j], 1, 64), io = __shfl_xor(ei[j], 1, 64);
            float sr = er[j] + ro, si = ei[j] + io;
            float dr = ro - er[j], di = io - ei[j];
            float tr, ti;
            if      (j == 0) { tr = dr;               ti = di; }
            else if (j == 1) { tr = R2_F * (dr + di); ti = R2_F * (di - dr); }
            else if (j == 2) { tr = di;               ti = -dr; }
            else             { tr = R2_F * (di - dr); ti = -R2_F * (dr + di); }
            er[j] = rb ? tr : sr; ei[j] = rb ? ti : si;
        }
    };

    auto stage21 = [&](float er[4], float ei[4]) {  // local s=2 then s=1
        float ar, ai, br, bi, dr, di;
        ar = er[0]; ai = ei[0]; br = er[2]; bi = ei[2];
        er[0] = ar + br; ei[0] = ai + bi; er[2] = ar - br; ei[2] = ai - bi;
        ar = er[1]; ai = ei[1]; br = er[3]; bi = ei[3];
        er[1] = ar + br; ei[1] = ai + bi;
        dr = ar - br; di = ai - bi; er[3] = di; ei[3] = -dr;   // * (-i)
        ar = er[0]; ai = ei[0]; br = er[1]; bi = ei[1];
        er[0] = ar + br; ei[0] = ai + bi; er[1] = ar - br; ei[1] = ai - bi;
        ar = er[2]; ai = ei[2]; br = er[3]; bi = ei[3];
        er[2] = ar + br; ei[2] = ai + bi; er[3] = ar - br; ei[3] = ai - bi;
    };

    auto scatter = [&](const float er[4], const float ei[4], float2* Z) {
        #pragma unroll
        for (int j = 0; j < 4; ++j) {
            int p   = (lane << 2) | j;
            int rev = __brev((unsigned)p) >> 24;
            Z[zidx(rev)] = make_float2(er[j], ei[j]);
        }
    };

    auto untangle = [&](const float2* Z, const float* tfp, int row) {
        #pragma unroll
        for (int m = 0; m < 4; ++m) {
            int k = lane + (m << 6);
            if (k == 0) {
                float2 z0 = Z[0];
                stg[row][0] = __floats2half2_rn(clamp01(tfp[0])   * (z0.x + z0.y),
                                                clamp01(tfp[256]) * (z0.x - z0.y));
            } else {
                float2 zk = Z[zidx(k)], zm = Z[zidx(256 - k)];
                float Er = 0.5f * (zk.x + zm.x), Ei = 0.5f * (zk.y - zm.y);
                float Or = 0.5f * (zk.y + zm.y), Oi = -0.5f * (zk.x - zm.x);
                float cv, sv;
                if      (m == 0) { cv = uc;               sv = us; }
                else if (m == 1) { cv = R2_F * (uc + us); sv = R2_F * (us - uc); }
                else if (m == 2) { cv = us;               sv = -uc; }
                else             { cv = R2_F * (us - uc); sv = -R2_F * (uc + us); }
                float Xr = Er + cv * Or - sv * Oi;
                float Xi = Ei + cv * Oi + sv * Or;
                float rk = clamp01(tfp[k]);
                stg[row][k] = __floats2half2_rn(rk * Xr, rk * Xi);
            }
        }
    };

    for (int q = 0; q < 2; ++q) {
        const int rA   = (q << 3) + (wv << 1);     // rows rA, rA+1
        const int posA = pos0 + rA, posB = posA + 1;

        float erA[4], eiA[4], erB[4], eiB[4];
        envload(posA, rA,     erA, eiA);
        envload(posB, rA + 1, erB, eiB);

        // ----- 5 cross-lane stages with derived twiddles (A,B interleaved) --
        #pragma unroll
        for (int t = 0; t < 5; ++t) {
            const int  lm = 32 >> t;
            const bool rb = (lane & lm) != 0;
            const float c0 = bc[t], s0 = bs[t];
            #pragma unroll
            for (int j = 0; j < 4; ++j) {
                float c, sn;
                if (j == 0) { c = c0; sn = s0; }
                else {
                    const float wc = wjc[t][j - 1], ws = wjs[t][j - 1];
                    c  = c0 * wc - s0 * ws;
                    sn = c0 * ws + s0 * wc;
                }
                {   // A
                    float ro = __shfl_xor(erA[j], lm, 64), io = __shfl_xor(eiA[j], lm, 64);
                    float sr = erA[j] + ro, si = eiA[j] + io;
                    float dr = ro - erA[j], di = io - eiA[j];
                    float tr = c * dr - sn * di, ti = c * di + sn * dr;
                    erA[j] = rb ? tr : sr; eiA[j] = rb ? ti : si;
                }
                {   // B
                    float ro = __shfl_xor(erB[j], lm, 64), io = __shfl_xor(eiB[j], lm, 64);
                    float sr = erB[j] + ro, si = eiB[j] + io;
                    float dr = ro - erB[j], di = io - eiB[j];
                    float tr = c * dr - sn * di, ti = c * di + sn * dr;
                    erB[j] = rb ? tr : sr; eiB[j] = rb ? ti : si;
                }
            }
        }
        stage4(erA, eiA);  stage4(erB, eiB);
        stage21(erA, eiA); stage21(erB, eiB);

        scatter(erA, eiA, &Zb[wv][0][0]);
        scatter(erB, eiB, &Zb[wv][1][0]);
        // wave-private Zb: intra-wave LDS ordering, no barrier needed
        untangle(&Zb[wv][0][0], tf + (size_t)posA * 257, rA);
        untangle(&Zb[wv][1][0], tf + (size_t)posB * 257, rA + 1);
    }

    __syncthreads();
    {   // single coalesced write-out: 16 consecutive pos (64B line) per k
        const int rr = tid & 15, kb = tid >> 4;
        const size_t pbase = (size_t)pos0 + rr;
        #pragma unroll
        for (int i = 0; i < 16; ++i) {
            int k = kb + (i << 4);
            Hbuf[(size_t)k * NPOS + pbase] = stg[rr][k];
        }
    }
}

// ---------------------------------------------------------------------------
// K2: frequency-domain scan. Block k owns bin-plane k: 32x32 complex state.
// Double-buffered LDS tile -> 1 barrier/step; prefetch depth 2.
// ---------------------------------------------------------------------------
__global__ __launch_bounds__(1024) void k2_scan(
    const __half2* __restrict__ Hbuf,  // [NBIN][NPOS]
    float2* __restrict__ Mbuf)         // [NB][NBIN]
{
    __shared__ float2 sfb[2][32][33];
    const int k   = blockIdx.x;
    const int tid = threadIdx.x;
    const int h   = tid >> 5, w = tid & 31;
    const int hm = (h == 0) ? 1 : h - 1, hp = (h == 31) ? 30 : h + 1;
    const int wm = (w == 0) ? 1 : w - 1, wp = (w == 31) ? 30 : w + 1;

    const __half2* Hp = Hbuf + (size_t)k * NPOS + tid;
    __half2 c0 = Hp[0];
    __half2 c1 = Hp[1024];
    float fr = 0.0f, fi = 0.0f;

    for (int b = 0; b < NB; ++b) {
        float2 hv = __half22float2(c0);
        c0 = c1;
        if (b + 2 < NB) c1 = Hp[(size_t)(b + 2) << 10];
        fr += hv.x; fi += hv.y;
        if (tid == 528) Mbuf[b * NBIN + k] = make_float2(fr, fi); // mic BEFORE box
        sfb[b & 1][h][w] = make_float2(fr, fi);
        __syncthreads();
        float sr = 0.0f, si = 0.0f; float2 v;
        v = sfb[b & 1][hm][wm]; sr += v.x; si += v.y;
        v = sfb[b & 1][hm][w ]; sr += v.x; si += v.y;
        v = sfb[b & 1][hm][wp]; sr += v.x; si += v.y;
        v = sfb[b & 1][h ][wm]; sr += v.x; si += v.y;
        v = sfb[b & 1][h ][w ]; sr += v.x; si += v.y;
        v = sfb[b & 1][h ][wp]; sr += v.x; si += v.y;
        v = sfb[b & 1][hp][wm]; sr += v.x; si += v.y;
        v = sfb[b & 1][hp][w ]; sr += v.x; si += v.y;
        v = sfb[b & 1][hp][wp]; sr += v.x; si += v.y;
        fr = sr * (1.0f / 9.0f); fi = si * (1.0f / 9.0f);
    }
}

// ---------------------------------------------------------------------------
// K3: per-block-b inverse rDFT (512 samples from 257 Hermitian bins, 1/512).
// ---------------------------------------------------------------------------
__global__ __launch_bounds__(512) void k3_idft(
    const float2* __restrict__ Mbuf,
    float* __restrict__ out)
{
    __shared__ float2 lm[256];
    const int b = blockIdx.x;
    const int t = threadIdx.x;
    if (t < 256) lm[t] = Mbuf[b * NBIN + t];
    __syncthreads();
    float acc = 0.0f;
    #pragma unroll 4
    for (int k = 1; k < 256; ++k) {
        int   ph  = (k * t) & 511;
        float ang = (float)ph * (PI_F / 256.0f);
        float sv, cv; __sincosf(ang, &sv, &cv);
        float2 m = lm[k];
        acc += m.x * cv - m.y * sv;
    }
    float m0 = lm[0].x, m256 = lm[0].y;
    float r  = m0 + ((t & 1) ? -m256 : m256) + 2.0f * acc;
    out[(b << 9) + t] = r * (1.0f / 512.0f);
}

extern "C" void kernel_launch(void* const* d_in, const int* in_sizes, int n_in,
                              void* d_out, int out_size, void* d_ws, size_t ws_size,
                              hipStream_t stream)
{
    const float* tf  = (const float*)d_in[1]; // (128,32,32,257)
    const float* imp = (const float*)d_in[2]; // (128,32,32,16)
    const float* nz  = (const float*)d_in[3]; // (128,32,32,512)
    float* out = (float*)d_out;

    const size_t hbytes = (size_t)NBIN * NPOS * sizeof(__half2);  // 134.2 MB
    const size_t mbytes = (size_t)NB * NBIN * sizeof(float2);     // 256 KB
    if (ws_size < hbytes + mbytes) {
        hipMemsetAsync(d_out, 0xFF, (size_t)out_size * sizeof(float), stream);
        return;
    }
    __half2* Hbuf = (__half2*)d_ws;
    float2*  Mbuf = (float2*)((char*)d_ws + hbytes);

    k1_fft<<<NPOS / 16, 256, 0, stream>>>(tf, imp, nz, Hbuf);
    k2_scan<<<NBIN, 1024, 0, stream>>>(Hbuf, Mbuf);
    k3_idft<<<NB, 512, 0, stream>>>(Mbuf, out);
}